// Round 13
// baseline (734.075 us; speedup 1.0000x reference)
//
#include <hip/hip_runtime.h>
#include <math.h>

#define KDIM 1024
#define HID 256
#define NE 16
#define ROWS_BLK 64
#define KCH 32
#define NCHUNK 32
#define CH_BYTES 32768            // B chunk image: [p][kg][col] 16B granules
#define W2T_PLANE (NE * HID)
#define ABUF(i) (((i) & 3) * 8192)            // A ring: 4 x 8KB @0
#define BBUF(i) (32768 + ((i) & 3) * 32768)   // B ring: 4 x 32KB @32768
#define SMEM_BYTES 163840

typedef __attribute__((ext_vector_type(4))) _Float16 f16x4;
typedef __attribute__((ext_vector_type(8))) _Float16 f16x8;
typedef __attribute__((ext_vector_type(16))) float f32x16;
typedef __attribute__((ext_vector_type(4))) float f32x4;

struct Frag6 { f16x8 a1, a2, b1c0, b2c0, b1c1, b2c1; };

__device__ __forceinline__ void gld16(const void* g, void* s) {
  __builtin_amdgcn_global_load_lds(
      (const __attribute__((address_space(1))) void*)g,
      (__attribute__((address_space(3))) void*)s, 16, 0, 0);
}

// R3/R6-R12-proven planes: p1 = fl16(v), p2 = fl16((v - p1)*4096).
__global__ void prep_w1(const float* __restrict__ W1, _Float16* __restrict__ img) {
  int idx = blockIdx.x * 256 + threadIdx.x;   // 0..32767
  int col = idx & 255, kgl = idx >> 8;        // kgl 0..127
  int c = kgl >> 2, kg = kgl & 3, k8 = kgl * 8;
  f16x8 p1, p2;
#pragma unroll
  for (int i = 0; i < 8; ++i) {
    float v = W1[(size_t)(k8 + i) * HID + col];
    _Float16 a = (_Float16)v;
    _Float16 b = (_Float16)((v - (float)a) * 4096.0f);
    p1[i] = a; p2[i] = b;
  }
  size_t off = (size_t)c * 16384 + (size_t)kg * 2048 + (size_t)col * 8;  // shorts
  *(f16x8*)(img + off) = p1;
  *(f16x8*)(img + off + 8192) = p2;
}

__global__ void prep_w2(const float* __restrict__ W2, _Float16* __restrict__ w2t) {
  int idx = blockIdx.x * 256 + threadIdx.x;   // 0..4095
  int e = idx & 15, k = idx >> 4;
  float v = W2[(size_t)k * NE + e];
  _Float16 a = (_Float16)v;
  _Float16 b = (_Float16)((v - (float)a) * 4096.0f);
  w2t[(size_t)e * HID + k] = a;
  w2t[W2T_PLANE + (size_t)e * HID + k] = b;
}

__global__ __launch_bounds__(512, 2) void fused_router(
    const float* __restrict__ x, const _Float16* __restrict__ w1img,
    const _Float16* __restrict__ w2t, const float* __restrict__ bias1,
    const float* __restrict__ bias2, float* __restrict__ outA,
    float* __restrict__ outL)
{
  extern __shared__ char smem[];
  const int t = threadIdx.x, l = t & 63, w = t >> 6;
  const int rowg = w >> 2, colg = w & 3;     // 2 x 4 waves: 64 rows x 256 cols
  const int l31 = l & 31, hi = l >> 5;
  const int R0 = blockIdx.x * ROWS_BLK;
  const int arow = rowg * 32 + l31;
  const int bcol0 = colg * 64 + l31;         // + 32*ct

  // x loader: row xr = t>>3 (0..63), float-quad xq = t&7 (k = xq*4..+3)
  const int xr = t >> 3, xq = t & 7;
  const float* xbase = x + (size_t)(R0 + xr) * KDIM + xq * 4;
  const int akg = xq >> 1, asub = (xq & 1) * 8;

  // B stager: thread t copies image bytes t*16 (+ i*8192), linear
  const char* ibase = (const char*)w1img + t * 16;

  f32x16 acc0[2], accA[2];
#pragma unroll
  for (int ct = 0; ct < 2; ++ct)
#pragma unroll
    for (int j = 0; j < 16; ++j) { acc0[ct][j] = 0.f; accA[ct][j] = 0.f; }

  float4 xv0, xv1;
  Frag6 fA, fB;

#define XLOADV(XV_, C_) do { XV_ = *(const float4*)(xbase + (size_t)(C_) * KCH); } while (0)

#define BSTAGE(C_) do {                                                       \
    const char* is_ = ibase + (size_t)(C_) * CH_BYTES;                        \
    char* bd_ = smem + BBUF(C_) + t * 16;                                     \
    gld16(is_,         bd_);                                                  \
    gld16(is_ + 8192,  bd_ + 8192);                                           \
    gld16(is_ + 16384, bd_ + 16384);                                          \
    gld16(is_ + 24576, bd_ + 24576);                                          \
  } while (0)

#define ASPLITV(XV_, C_) do {                                                 \
    float vals_[4] = {(XV_).x, (XV_).y, (XV_).z, (XV_).w};                    \
    f16x4 pa_, pb_;                                                           \
    _Pragma("unroll") for (int j_ = 0; j_ < 4; ++j_) {                        \
      float v_ = vals_[j_];                                                   \
      _Float16 a_ = (_Float16)v_;                                             \
      _Float16 b_ = (_Float16)((v_ - (float)a_) * 4096.0f);                   \
      pa_[j_] = a_; pb_[j_] = b_;                                             \
    }                                                                         \
    int ao_ = ABUF(C_) + akg * 1024 + xr * 16 + asub;                         \
    *(f16x4*)(smem + ao_) = pa_;                                              \
    *(f16x4*)(smem + ao_ + 4096) = pb_;                                       \
  } while (0)

#define FRAG6(F_, C_, S_) do {                                                \
    const int gg_ = 2 * (S_) + hi;                                            \
    int ao_ = ABUF(C_) + gg_ * 1024 + arow * 16;                              \
    (F_).a1 = *(const f16x8*)(smem + ao_);                                    \
    (F_).a2 = *(const f16x8*)(smem + ao_ + 4096);                             \
    int bo_ = BBUF(C_) + gg_ * 4096 + bcol0 * 16;                             \
    (F_).b1c0 = *(const f16x8*)(smem + bo_);                                  \
    (F_).b2c0 = *(const f16x8*)(smem + bo_ + 16384);                          \
    (F_).b1c1 = *(const f16x8*)(smem + bo_ + 512);                            \
    (F_).b2c1 = *(const f16x8*)(smem + bo_ + 16384 + 512);                    \
  } while (0)

#define MFMA6(F_) do {                                                        \
    __builtin_amdgcn_s_setprio(1);                                            \
    acc0[0] = __builtin_amdgcn_mfma_f32_32x32x16_f16((F_).a1, (F_).b1c0, acc0[0], 0, 0, 0); \
    accA[0] = __builtin_amdgcn_mfma_f32_32x32x16_f16((F_).a1, (F_).b2c0, accA[0], 0, 0, 0); \
    accA[0] = __builtin_amdgcn_mfma_f32_32x32x16_f16((F_).a2, (F_).b1c0, accA[0], 0, 0, 0); \
    acc0[1] = __builtin_amdgcn_mfma_f32_32x32x16_f16((F_).a1, (F_).b1c1, acc0[1], 0, 0, 0); \
    accA[1] = __builtin_amdgcn_mfma_f32_32x32x16_f16((F_).a1, (F_).b2c1, accA[1], 0, 0, 0); \
    accA[1] = __builtin_amdgcn_mfma_f32_32x32x16_f16((F_).a2, (F_).b1c1, accA[1], 0, 0, 0); \
    __builtin_amdgcn_s_setprio(0);                                            \
  } while (0)

// body(c): stage(c+2), split(c+2), x(c+3); MFMA(c,s0) on FCUR (prefetched);
// lookahead-read frags(c+1,s0) -> FNXT (stays in flight across the barrier);
// own vmcnt gate certifies stage(c+2) before the barrier publishes it.
#define BODY(C_, FCUR_, FNXT_, XSP_, XLD_, STG_, XL_, LA_, VMSTR_) do {       \
    if (STG_) { BSTAGE((C_) + 2); ASPLITV(XSP_, (C_) + 2); }                  \
    __builtin_amdgcn_sched_barrier(0);  /* pin ds_writes oldest */            \
    if (XL_) XLOADV(XLD_, (C_) + 3);                                          \
    Frag6 fs1_; FRAG6(fs1_, (C_), 1);                                         \
    MFMA6(FCUR_);                                                             \
    if (LA_) FRAG6(FNXT_, (C_) + 1, 0);                                       \
    MFMA6(fs1_);                                                              \
    __builtin_amdgcn_sched_barrier(0);                                        \
    asm volatile("s_waitcnt vmcnt(" VMSTR_ ")" ::: "memory");                 \
    asm volatile("s_waitcnt lgkmcnt(6)" ::: "memory");                        \
    __builtin_amdgcn_sched_barrier(0);                                        \
    __builtin_amdgcn_s_barrier();                                             \
  } while (0)

  // ---- prologue ----
  XLOADV(xv0, 0);
  XLOADV(xv1, 1);
  BSTAGE(0);
  BSTAGE(1);
  ASPLITV(xv0, 0);
  ASPLITV(xv1, 1);
  XLOADV(xv0, 2);
  __builtin_amdgcn_sched_barrier(0);
  asm volatile("s_waitcnt vmcnt(1)" ::: "memory");    // stages 0,1 landed
  asm volatile("s_waitcnt lgkmcnt(0)" ::: "memory");  // splits 0,1 retired
  __builtin_amdgcn_sched_barrier(0);
  __builtin_amdgcn_s_barrier();
  FRAG6(fA, 0, 0);

  // ---- steady loop: bodies 0..27 (period-2), peel 28..31 ----
#pragma unroll 1
  for (int cb = 0; cb < NCHUNK - 4; cb += 2) {
    BODY(cb,     fA, fB, xv0, xv1, 1, 1, 1, "1");
    BODY(cb + 1, fB, fA, xv1, xv0, 1, 1, 1, "1");
  }
  BODY(28, fA, fB, xv0, xv1, 1, 1, 1, "1");
  BODY(29, fB, fA, xv1, xv0, 1, 0, 1, "0");
  BODY(30, fA, fB, xv0, xv1, 0, 0, 1, "0");
  BODY(31, fB, fA, xv1, xv0, 0, 0, 0, "0");

  // ---- epilogue: R6-verbatim single 64-row pass ----
  const float c12 = 1.0f / 4096.0f;
  const int tok = l & 15, g2 = l >> 4;

  __syncthreads();
#pragma unroll
  for (int ct = 0; ct < 2; ++ct) {
    int col = bcol0 + 32 * ct;
    float bc = bias1[col];
    int cg = col >> 3, cb = (col & 7) * 2;
#pragma unroll
    for (int r = 0; r < 16; ++r) {
      int tloc = rowg * 32 + (r & 3) + 8 * (r >> 2) + 4 * hi;   // 0..63
      float v = acc0[ct][r] + c12 * accA[ct][r] + bc;
      v = v > 0.f ? v : expm1f(v);
      _Float16 h1 = (_Float16)v;
      _Float16 h2 = (_Float16)((v - (float)h1) * 4096.0f);
      int off = tloc * 512 + ((cg ^ (tloc & 7)) << 4) + cb;
      *(_Float16*)(smem + off) = h1;
      *(_Float16*)(smem + 32768 + off) = h2;
    }
  }
  __syncthreads();

  if (w < 4) {
    int tloc = w * 16 + tok;                 // 0..63
    f32x4 L0, LA;
#pragma unroll
    for (int j = 0; j < 4; ++j) { L0[j] = 0.f; LA[j] = 0.f; }
    const _Float16* w2a = w2t + (size_t)tok * HID;
    const _Float16* w2b = w2a + W2T_PLANE;
#pragma unroll
    for (int kt = 0; kt < 8; ++kt) {
      int gg = (kt * 4 + g2) ^ (tloc & 7);
      f16x8 hb1 = *(const f16x8*)(smem + tloc * 512 + (gg << 4));
      f16x8 hb2 = *(const f16x8*)(smem + 32768 + tloc * 512 + (gg << 4));
      f16x8 wa = *(const f16x8*)(w2a + kt * 32 + 8 * g2);
      f16x8 wb = *(const f16x8*)(w2b + kt * 32 + 8 * g2);
      L0 = __builtin_amdgcn_mfma_f32_16x16x32_f16(wa, hb1, L0, 0, 0, 0);
      LA = __builtin_amdgcn_mfma_f32_16x16x32_f16(wa, hb2, LA, 0, 0, 0);
      LA = __builtin_amdgcn_mfma_f32_16x16x32_f16(wb, hb1, LA, 0, 0, 0);
    }
    float4 b2v = *(const float4*)(bias2 + 4 * g2);
    float L[4];
    L[0] = L0[0] + c12 * LA[0] + b2v.x;
    L[1] = L0[1] + c12 * LA[1] + b2v.y;
    L[2] = L0[2] + c12 * LA[2] + b2v.z;
    L[3] = L0[3] + c12 * LA[3] + b2v.w;

    float o1[4], o2[4], o3[4];
#pragma unroll
    for (int j = 0; j < 4; ++j) o1[j] = __shfl_xor(L[j], 16);
#pragma unroll
    for (int j = 0; j < 4; ++j) o2[j] = __shfl_xor(L[j], 32);
#pragma unroll
    for (int j = 0; j < 4; ++j) o3[j] = __shfl_xor(o1[j], 32);

    float all16[16];
#pragma unroll
    for (int cq = 0; cq < 4; ++cq) {
      int xg = cq ^ g2;
#pragma unroll
      for (int j = 0; j < 4; ++j) {
        float v = L[j];
        v = (xg == 1) ? o1[j] : v;
        v = (xg == 2) ? o2[j] : v;
        v = (xg == 3) ? o3[j] : v;
        all16[cq * 4 + j] = v;
      }
    }

    int i1 = 0; float m1 = all16[0];
#pragma unroll
    for (int e = 1; e < 16; ++e) { if (all16[e] > m1) { m1 = all16[e]; i1 = e; } }
    int i2 = -1; float m2 = -INFINITY;
#pragma unroll
    for (int e = 0; e < 16; ++e) { if (e != i1 && all16[e] > m2) { m2 = all16[e]; i2 = e; } }
    float ex = expf(m2 - m1);
    float sden = 1.f + ex;
    float A1 = 1.f / sden;
    float A2 = ex / sden;

    int e0 = 4 * g2;
    float4 alv;
    alv.x = (e0 + 0 == i1) ? A1 : ((e0 + 0 == i2) ? A2 : 0.f);
    alv.y = (e0 + 1 == i1) ? A1 : ((e0 + 1 == i2) ? A2 : 0.f);
    alv.z = (e0 + 2 == i1) ? A1 : ((e0 + 2 == i2) ? A2 : 0.f);
    alv.w = (e0 + 3 == i1) ? A1 : ((e0 + 3 == i2) ? A2 : 0.f);

    size_t orow = (size_t)(R0 + tloc);
    float4 lgv; lgv.x = L[0]; lgv.y = L[1]; lgv.z = L[2]; lgv.w = L[3];
    *(float4*)(outL + orow * NE + e0) = lgv;
    *(float4*)(outA + orow * NE + e0) = alv;
  }
#undef XLOADV
#undef BSTAGE
#undef ASPLITV
#undef FRAG6
#undef MFMA6
#undef BODY
}

extern "C" void kernel_launch(void* const* d_in, const int* in_sizes, int n_in,
                              void* d_out, int out_size, void* d_ws, size_t ws_size,
                              hipStream_t stream) {
  const float* x  = (const float*)d_in[0];
  const float* W1 = (const float*)d_in[1];
  const float* b1 = (const float*)d_in[2];
  const float* W2 = (const float*)d_in[3];
  const float* b2 = (const float*)d_in[4];
  _Float16* w1img = (_Float16*)d_ws;
  _Float16* w2t = w1img + (size_t)NCHUNK * (CH_BYTES / 2);
  float* outA = (float*)d_out;
  const size_t n_tok = (size_t)in_sizes[0] / KDIM;
  float* outL = outA + n_tok * NE;

  prep_w1<<<dim3(128), dim3(256), 0, stream>>>(W1, w1img);
  prep_w2<<<dim3(16), dim3(256), 0, stream>>>(W2, w2t);

  hipFuncSetAttribute((const void*)fused_router,
                      hipFuncAttributeMaxDynamicSharedMemorySize, SMEM_BYTES);
  fused_router<<<dim3((unsigned)(n_tok / ROWS_BLK)), dim3(512), SMEM_BYTES, stream>>>(
      x, w1img, w2t, b1, b2, outA, outL);
}